// Round 1
// baseline (16.406 us; speedup 1.0000x reference)
//
#include <hip/hip_runtime.h>

// RelationNetwork collapsed algebraically:
//   out[b,f] = bf[f] + sum_e Wf[f,e] * ( P*bg[e]
//            + sum_d Wg[e,d]    * X_A[b,d]
//            + sum_d Wg[e,64+d] * X_B[b,d] )
//   X_A[b,d] = sum_i (N-1-i)*obj[b,i,d]   (ii[p]=i appears N-1-i times)
//   X_B[b,d] = sum_i  i     *obj[b,i,d]   (jj[p]=j appears j times)

#define NB 4
#define NN 1024
#define DD 64
#define NC 16                    // row-chunks per batch
#define ROWS_PER_CHUNK (NN / NC) // 64

__global__ __launch_bounds__(256) void rn_partial(const float* __restrict__ obj,
                                                  float* __restrict__ pA,
                                                  float* __restrict__ pB) {
    const int blk = blockIdx.x;
    const int b   = blk >> 4;   // blk / NC
    const int c   = blk & 15;   // blk % NC
    const int t   = threadIdx.x;
    const int d   = t & 63;
    const int sub = t >> 6;     // 0..3 (wave index)

    const float* base = obj + (size_t)b * NN * DD;
    const int i0 = c * ROWS_PER_CHUNK;

    float accA = 0.f, accB = 0.f;
    #pragma unroll
    for (int k = 0; k < ROWS_PER_CHUNK / 4; ++k) {
        const int i = i0 + sub + 4 * k;
        const float x = base[(size_t)i * DD + d];   // 64 lanes coalesced over d
        accA += (float)(NN - 1 - i) * x;
        accB += (float)i * x;
    }

    __shared__ float sA[4][64];
    __shared__ float sB[4][64];
    sA[sub][d] = accA;
    sB[sub][d] = accB;
    __syncthreads();

    if (sub == 0) {
        pA[(b * NC + c) * DD + d] = sA[0][d] + sA[1][d] + sA[2][d] + sA[3][d];
    } else if (sub == 1) {
        pB[(b * NC + c) * DD + d] = sB[0][d] + sB[1][d] + sB[2][d] + sB[3][d];
    }
}

__global__ __launch_bounds__(256) void rn_final(const float* __restrict__ pA,
                                                const float* __restrict__ pB,
                                                const float* __restrict__ Wg,
                                                const float* __restrict__ bg,
                                                const float* __restrict__ Wf,
                                                const float* __restrict__ bf,
                                                float* __restrict__ out) {
    const int t = threadIdx.x;
    const int b = t >> 6;   // 0..3
    const int x = t & 63;   // d, then e, then f

    __shared__ float sXA[4][64];
    __shared__ float sXB[4][64];
    __shared__ float sS[4][64];

    // Phase 1: reduce the 16 chunk-partials -> X_A[b,d], X_B[b,d]
    float a = 0.f, bb = 0.f;
    #pragma unroll
    for (int c = 0; c < NC; ++c) {
        a  += pA[(b * NC + c) * DD + x];
        bb += pB[(b * NC + c) * DD + x];
    }
    sXA[b][x] = a;
    sXB[b][x] = bb;
    __syncthreads();

    // Phase 2: s[b,e] = P*bg[e] + sum_d Wg[e,d]*XA[b,d] + Wg[e,64+d]*XB[b,d]
    const float PAIRS = 523776.f;  // 1024*1023/2
    float s = PAIRS * bg[x];
    #pragma unroll
    for (int dd = 0; dd < 64; ++dd) {
        s += Wg[x * 128 + dd]      * sXA[b][dd]
           + Wg[x * 128 + 64 + dd] * sXB[b][dd];
    }
    sS[b][x] = s;
    __syncthreads();

    // Phase 3: out[b,f] = bf[f] + sum_e Wf[f,e] * s[b,e]
    float o = bf[x];
    #pragma unroll
    for (int e = 0; e < 64; ++e) {
        o += Wf[x * 64 + e] * sS[b][e];
    }
    out[b * 64 + x] = o;
}

extern "C" void kernel_launch(void* const* d_in, const int* in_sizes, int n_in,
                              void* d_out, int out_size, void* d_ws, size_t ws_size,
                              hipStream_t stream) {
    const float* obj = (const float*)d_in[0];
    const float* Wg  = (const float*)d_in[1];
    const float* bg  = (const float*)d_in[2];
    const float* Wf  = (const float*)d_in[3];
    const float* bf  = (const float*)d_in[4];
    float* outp = (float*)d_out;

    float* pA = (float*)d_ws;              // [NB][NC][DD] floats = 16 KB
    float* pB = pA + NB * NC * DD;         // [NB][NC][DD] floats = 16 KB

    rn_partial<<<NB * NC, 256, 0, stream>>>(obj, pA, pB);
    rn_final<<<1, 256, 0, stream>>>(pA, pB, Wg, bg, Wf, bf, outp);
}

// Round 3
// 14.302 us; speedup vs baseline: 1.1471x; 1.1471x over previous
//
#include <hip/hip_runtime.h>

// RelationNetwork collapsed algebraically (pair sum is linear):
//   X_A[b,d] = sum_i (N-1-i)*obj[b,i,d]
//   X_B[b,d] = sum_i  i     *obj[b,i,d]
//   s[b,e]   = P*bg[e] + sum_d Wg[e,d]*X_A[b,d] + Wg[e,64+d]*X_B[b,d]
//   out[b,f] = bf[f] + sum_e Wf[f,e]*s[b,e]
//
// Single dispatch, 64 blocks. Cross-block communication (partials + flags)
// goes ENTIRELY through agent-scope atomics: per-XCD L2s are not coherent,
// and the harness's 0xAA ws-poison leaves stale lines valid in the combiner's
// L2 — plain loads after an acquire were served stale (R2 post-timing fail).
// Atomic agent-scope ops bypass the non-coherent caches to the coherent point.

#define NB 4
#define NN 1024
#define DD 64
#define NC 16
#define NWG (NB * NC)       // 64 blocks
#define RPC (NN / NC)       // 64 rows per chunk
#define MAGIC 0x5A17C0DEu

__global__ __launch_bounds__(256) void rn_fused(const float* __restrict__ obj,
                                                const float* __restrict__ Wg,
                                                const float* __restrict__ bg,
                                                const float* __restrict__ Wf,
                                                const float* __restrict__ bf,
                                                float* __restrict__ out,
                                                float* __restrict__ pA,
                                                float* __restrict__ pB,
                                                unsigned int* __restrict__ flags) {
    const int blk = blockIdx.x;
    const int b   = blk >> 4;   // batch
    const int c   = blk & 15;   // chunk
    const int t   = threadIdx.x;
    const int dq  = t & 15;     // float4 column (d = dq*4..dq*4+3)
    const int r   = t >> 4;     // 0..15 row-in-pass

    // ---- phase 1: weighted chunk partial sums (float4-vectorized) ----
    const float4* base4 = (const float4*)(obj + (size_t)b * NN * DD); // [NN][16]
    float4 aA = {0.f, 0.f, 0.f, 0.f};
    float4 aB = {0.f, 0.f, 0.f, 0.f};
    #pragma unroll
    for (int p = 0; p < 4; ++p) {
        const int i = c * RPC + p * 16 + r;
        const float4 x = base4[i * 16 + dq];
        const float wA = (float)(NN - 1 - i);
        const float wB = (float)i;
        aA.x += wA * x.x; aA.y += wA * x.y; aA.z += wA * x.z; aA.w += wA * x.w;
        aB.x += wB * x.x; aB.y += wB * x.y; aB.z += wB * x.z; aB.w += wB * x.w;
    }

    __shared__ float4 s4A[16][16];
    __shared__ float4 s4B[16][16];
    s4A[r][dq] = aA;
    s4B[r][dq] = aB;
    __syncthreads();

    if (t < DD) {
        const int q = t >> 2, k = t & 3;
        float sa = 0.f, sb = 0.f;
        #pragma unroll
        for (int rr = 0; rr < 16; ++rr) {
            sa += ((const float*)&s4A[rr][q])[k];
            sb += ((const float*)&s4B[rr][q])[k];
        }
        // agent-scope stores: land at the coherent point, not a private L2
        __hip_atomic_store(&pA[blk * DD + t], sa, __ATOMIC_RELAXED,
                           __HIP_MEMORY_SCOPE_AGENT);
        __hip_atomic_store(&pB[blk * DD + t], sb, __ATOMIC_RELAXED,
                           __HIP_MEMORY_SCOPE_AGENT);
    }
    __syncthreads();   // all partial stores sequenced before the flag release

    if (blk != 0) {
        if (t == 0)
            __hip_atomic_store(&flags[blk], MAGIC, __ATOMIC_RELEASE,
                               __HIP_MEMORY_SCOPE_AGENT);
        return;
    }

    // ---- block 0: wait for the other 63 workers ----
    if (t < NWG - 1) {
        while (__hip_atomic_load(&flags[t + 1], __ATOMIC_ACQUIRE,
                                 __HIP_MEMORY_SCOPE_AGENT) != MAGIC) {
            __builtin_amdgcn_s_sleep(2);
        }
    }
    __syncthreads();

    // reset flags for the next graph replay — ATOMIC, same coherence point
    // as the workers' MAGIC stores (never mix plain stores onto this line)
    if (t >= 1 && t < NWG)
        __hip_atomic_store(&flags[t], 0u, __ATOMIC_RELAXED,
                           __HIP_MEMORY_SCOPE_AGENT);

    // ---- phase 2: reduce partials -> X_A, X_B (agent-scope loads) ----
    const int fb = t >> 6;  // batch 0..3
    const int x  = t & 63;

    __shared__ float sXA[4][64];
    __shared__ float sXB[4][64];
    __shared__ float sS[4][64];

    float a = 0.f, bb = 0.f;
    #pragma unroll
    for (int cc = 0; cc < NC; ++cc) {
        a  += __hip_atomic_load(&pA[(fb * NC + cc) * DD + x], __ATOMIC_RELAXED,
                                __HIP_MEMORY_SCOPE_AGENT);
        bb += __hip_atomic_load(&pB[(fb * NC + cc) * DD + x], __ATOMIC_RELAXED,
                                __HIP_MEMORY_SCOPE_AGENT);
    }
    sXA[fb][x] = a;
    sXB[fb][x] = bb;
    __syncthreads();

    // ---- phase 3: s[b,e] = P*bg[e] + Wg_A[e,:].XA + Wg_B[e,:].XB ----
    const float PAIRS = 523776.f;  // 1024*1023/2
    float s = PAIRS * bg[x];
    #pragma unroll
    for (int dd = 0; dd < 64; ++dd) {
        s += Wg[x * 128 + dd]      * sXA[fb][dd]
           + Wg[x * 128 + 64 + dd] * sXB[fb][dd];
    }
    sS[fb][x] = s;
    __syncthreads();

    // ---- phase 4: out[b,f] = bf[f] + Wf[f,:].s[b,:] ----
    float o = bf[x];
    #pragma unroll
    for (int e = 0; e < 64; ++e) {
        o += Wf[x * 64 + e] * sS[fb][e];
    }
    out[fb * 64 + x] = o;
}

extern "C" void kernel_launch(void* const* d_in, const int* in_sizes, int n_in,
                              void* d_out, int out_size, void* d_ws, size_t ws_size,
                              hipStream_t stream) {
    const float* obj = (const float*)d_in[0];
    const float* Wg  = (const float*)d_in[1];
    const float* bg  = (const float*)d_in[2];
    const float* Wf  = (const float*)d_in[3];
    const float* bf  = (const float*)d_in[4];
    float* outp = (float*)d_out;

    float* pA = (float*)d_ws;                              // [64][64] floats
    float* pB = pA + NWG * DD;                             // [64][64] floats
    unsigned int* flags = (unsigned int*)(pB + NWG * DD);  // [64] u32

    rn_fused<<<NWG, 256, 0, stream>>>(obj, Wg, bg, Wf, bf, outp, pA, pB, flags);
}

// Round 4
// 10.478 us; speedup vs baseline: 1.5658x; 1.3649x over previous
//
#include <hip/hip_runtime.h>

// RelationNetwork collapsed algebraically (pair sum is linear):
//   X_A[b,d] = sum_i (N-1-i)*obj[b,i,d]
//   X_B[b,d] = sum_i  i     *obj[b,i,d]
//   s[b,e]   = P*bg[e] + sum_d Wg[e,d]*X_A[b,d] + Wg[e,64+d]*X_B[b,d]
//   out[b,f] = bf[f] + sum_e Wf[f,e]*s[b,e]
//
// Single dispatch, 65 blocks: 64 workers (chunk partials) + 1 combiner.
// Cross-block traffic (packed float2 partials + flags) is ENTIRELY
// agent-scope atomics (per-XCD L2s non-coherent; R2's plain-load version
// failed post-timing). Combiner prefetches Wg/Wf into LDS *transposed*
// while workers run — GEMV reads become conflict-free LDS instead of
// 64-line gathers on the combiner's critical path.

#define NB 4
#define NN 1024
#define DD 64
#define NC 16
#define NCHUNK (NB * NC)    // 64 worker blocks
#define RPC (NN / NC)       // 64 rows per chunk
#define MAGIC 0x5A17C0DEu

__global__ __launch_bounds__(256) void rn_fused(const float* __restrict__ obj,
                                                const float* __restrict__ Wg,
                                                const float* __restrict__ bg,
                                                const float* __restrict__ Wf,
                                                const float* __restrict__ bf,
                                                float* __restrict__ out,
                                                float2* __restrict__ pAB,
                                                unsigned int* __restrict__ flags) {
    const int blk = blockIdx.x;
    const int t   = threadIdx.x;

    if (blk != 0) {
        // ================= worker: one 64-row chunk =================
        const int chunk = blk - 1;
        const int b  = chunk >> 4;
        const int c  = chunk & 15;
        const int dq = t & 15;     // float4 column
        const int r  = t >> 4;     // 0..15

        __shared__ float4 s4A[16][16];
        __shared__ float4 s4B[16][16];

        const float4* base4 = (const float4*)(obj + (size_t)b * NN * DD);
        float4 aA = {0.f, 0.f, 0.f, 0.f};
        float4 aB = {0.f, 0.f, 0.f, 0.f};
        #pragma unroll
        for (int p = 0; p < 4; ++p) {
            const int i = c * RPC + p * 16 + r;
            const float4 x = base4[i * 16 + dq];
            const float wA = (float)(NN - 1 - i);
            const float wB = (float)i;
            aA.x += wA * x.x; aA.y += wA * x.y; aA.z += wA * x.z; aA.w += wA * x.w;
            aB.x += wB * x.x; aB.y += wB * x.y; aB.z += wB * x.z; aB.w += wB * x.w;
        }
        s4A[r][dq] = aA;
        s4B[r][dq] = aB;
        __syncthreads();

        if (t < DD) {
            const int q = t >> 2, k = t & 3;
            float sa = 0.f, sb = 0.f;
            #pragma unroll
            for (int rr = 0; rr < 16; ++rr) {
                sa += ((const float*)&s4A[rr][q])[k];
                sb += ((const float*)&s4B[rr][q])[k];
            }
            union { float2 f2; unsigned long long u; } pk;
            pk.f2 = make_float2(sa, sb);
            __hip_atomic_store((unsigned long long*)&pAB[chunk * DD + t], pk.u,
                               __ATOMIC_RELAXED, __HIP_MEMORY_SCOPE_AGENT);
        }
        __syncthreads();   // partial stores sequenced before flag release

        if (t == 0)
            __hip_atomic_store(&flags[blk], MAGIC, __ATOMIC_RELEASE,
                               __HIP_MEMORY_SCOPE_AGENT);
        return;
    }

    // ================= combiner (block 0) =================
    __shared__ float sWgT[2 * DD][DD + 1];  // Wg transposed: [dd][e]
    __shared__ float sWfT[DD][DD + 1];      // Wf transposed: [e][f]
    __shared__ float sXA[NB][DD];
    __shared__ float sXB[NB][DD];
    __shared__ float sS[NB][DD];

    // ---- prefetch weights into LDS (overlaps worker execution) ----
    const float4* wg4 = (const float4*)Wg;  // 64 rows x 32 float4
    #pragma unroll
    for (int k = 0; k < 8; ++k) {
        const int F = t + k * 256;          // 0..2047
        const float4 v = wg4[F];
        const int e = F >> 5, dq = F & 31;
        sWgT[dq * 4 + 0][e] = v.x;
        sWgT[dq * 4 + 1][e] = v.y;
        sWgT[dq * 4 + 2][e] = v.z;
        sWgT[dq * 4 + 3][e] = v.w;
    }
    const float4* wf4 = (const float4*)Wf;  // 64 rows x 16 float4
    #pragma unroll
    for (int k = 0; k < 4; ++k) {
        const int F = t + k * 256;          // 0..1023
        const float4 v = wf4[F];
        const int f = F >> 4, eq = F & 15;
        sWfT[eq * 4 + 0][f] = v.x;
        sWfT[eq * 4 + 1][f] = v.y;
        sWfT[eq * 4 + 2][f] = v.z;
        sWfT[eq * 4 + 3][f] = v.w;
    }

    // ---- wait for the 64 workers ----
    if (t < NCHUNK) {
        while (__hip_atomic_load(&flags[t + 1], __ATOMIC_ACQUIRE,
                                 __HIP_MEMORY_SCOPE_AGENT) != MAGIC) {
            __builtin_amdgcn_s_sleep(2);
        }
    }
    __syncthreads();

    // reset flags for the next graph replay (atomic — same line discipline)
    if (t < NCHUNK)
        __hip_atomic_store(&flags[t + 1], 0u, __ATOMIC_RELAXED,
                           __HIP_MEMORY_SCOPE_AGENT);

    // ---- reduce partials -> X_A, X_B (packed 64-bit atomic loads) ----
    const int fb = t >> 6;  // batch 0..3
    const int x  = t & 63;

    float a = 0.f, bb = 0.f;
    #pragma unroll
    for (int cc = 0; cc < NC; ++cc) {
        union { float2 f2; unsigned long long u; } pk;
        pk.u = __hip_atomic_load(
            (const unsigned long long*)&pAB[(fb * NC + cc) * DD + x],
            __ATOMIC_RELAXED, __HIP_MEMORY_SCOPE_AGENT);
        a  += pk.f2.x;
        bb += pk.f2.y;
    }
    sXA[fb][x] = a;
    sXB[fb][x] = bb;
    __syncthreads();

    // ---- s[b,e] = P*bg[e] + Wg_A[e,:].XA + Wg_B[e,:].XB (LDS, no conflicts) ----
    const float PAIRS = 523776.f;  // 1024*1023/2
    float s = PAIRS * bg[x];
    #pragma unroll
    for (int dd = 0; dd < 64; ++dd) {
        s += sWgT[dd][x]      * sXA[fb][dd]
           + sWgT[64 + dd][x] * sXB[fb][dd];
    }
    sS[fb][x] = s;
    __syncthreads();

    // ---- out[b,f] = bf[f] + Wf[f,:].s[b,:] ----
    float o = bf[x];
    #pragma unroll
    for (int e = 0; e < 64; ++e) {
        o += sWfT[e][x] * sS[fb][e];
    }
    out[fb * 64 + x] = o;
}

extern "C" void kernel_launch(void* const* d_in, const int* in_sizes, int n_in,
                              void* d_out, int out_size, void* d_ws, size_t ws_size,
                              hipStream_t stream) {
    const float* obj = (const float*)d_in[0];
    const float* Wg  = (const float*)d_in[1];
    const float* bg  = (const float*)d_in[2];
    const float* Wf  = (const float*)d_in[3];
    const float* bf  = (const float*)d_in[4];
    float* outp = (float*)d_out;

    float2* pAB = (float2*)d_ws;                           // [64][64] float2 = 32 KB
    unsigned int* flags = (unsigned int*)(pAB + NCHUNK * DD);  // [65] u32

    rn_fused<<<NCHUNK + 1, 256, 0, stream>>>(obj, Wg, bg, Wf, bf, outp, pAB, flags);
}